// Round 2
// baseline (252.343 us; speedup 1.0000x reference)
//
#include <hip/hip_runtime.h>
#include <stdint.h>

typedef __attribute__((ext_vector_type(8))) short short8;
typedef __attribute__((ext_vector_type(4))) float f32x4;

#define B_ 2
#define S_ 2048
#define D_ 1024
#define H_ 16
#define HD_ 64
#define BS_ (B_ * S_)   // 4096 rows
#define QKVN (3 * D_)   // 3072 fused N

#define NEGBIG (-1e30f)

__device__ __forceinline__ short f2bf(float f) {
    uint32_t u = __builtin_bit_cast(uint32_t, f);
    u = (u + 0x7FFFu + ((u >> 16) & 1u)) >> 16;
    return (short)u;
}

__device__ __forceinline__ void gload_lds16(const void* g, void* lds) {
    __builtin_amdgcn_global_load_lds(
        (const __attribute__((address_space(1))) void*)g,
        (__attribute__((address_space(3))) void*)lds, 16, 0, 0);
}

// ---------------- f32 -> bf16 cast (vectorized, grid-stride) ----------------
__global__ void castk(const float* __restrict__ s, short* __restrict__ d, int n8) {
    int i = blockIdx.x * blockDim.x + threadIdx.x;
    int stride = gridDim.x * blockDim.x;
    for (; i < n8; i += stride) {
        const float* sp = s + (size_t)i * 8;
        short8 o;
#pragma unroll
        for (int j = 0; j < 8; ++j) o[j] = f2bf(sp[j]);
        *(short8*)(d + (size_t)i * 8) = o;
    }
}

// ---------------- NT GEMM: C[M,N] = A[M,K] * Bt[N,K]^T (+bias) --------------
// 128x128 tile, BK=64, 4 waves (2x2), 16x16x32 bf16 MFMA.
// LDS linear row-major [128][64] bf16, XOR-swizzle (r&7)<<4 realized by
// pre-swizzling the global source of global_load_lds (rule 21: both sides).
template <bool F32OUT>
__global__ __launch_bounds__(256) void gemm_nt(
    const short* __restrict__ A, const short* __restrict__ Bt,
    void* __restrict__ Cout, const float* __restrict__ bias,
    int M, int N, int K) {
    __shared__ short As[128 * 64];
    __shared__ short Bs[128 * 64];
    const int tid = threadIdx.x;
    const int w = tid >> 6, l = tid & 63;
    const int lg = l >> 4, lr = l & 15;
    const int nbn = N >> 7;
    const int bm = blockIdx.x / nbn, bn = blockIdx.x % nbn;
    const int m0 = bm << 7, n0 = bn << 7;
    const int wm = (w >> 1) << 6, wn = (w & 1) << 6;

    f32x4 acc[4][4] = {};

    for (int kt = 0; kt < K; kt += 64) {
#pragma unroll
        for (int it = 0; it < 4; ++it) {
            int off = ((it * 4 + w) * 64 + l) * 16;  // byte offset in tile
            int row = off >> 7;                      // 128B per row (64 bf16)
            int scol = (off & 127) ^ ((row & 7) << 4);
            gload_lds16(A + (size_t)(m0 + row) * K + kt + (scol >> 1),
                        (char*)As + (it * 4 + w) * 1024);
            gload_lds16(Bt + (size_t)(n0 + row) * K + kt + (scol >> 1),
                        (char*)Bs + (it * 4 + w) * 1024);
        }
        __syncthreads();
        short8 af[4][2], bf[4][2];
#pragma unroll
        for (int f = 0; f < 4; ++f)
#pragma unroll
            for (int ks = 0; ks < 2; ++ks) {
                int ra = wm + f * 16 + lr;
                af[f][ks] = *(const short8*)((const char*)As + ra * 128 +
                                             ((lg * 16 + ks * 64) ^ ((ra & 7) << 4)));
                int rb = wn + f * 16 + lr;
                bf[f][ks] = *(const short8*)((const char*)Bs + rb * 128 +
                                             ((lg * 16 + ks * 64) ^ ((rb & 7) << 4)));
            }
#pragma unroll
        for (int mf = 0; mf < 4; ++mf)
#pragma unroll
            for (int nf = 0; nf < 4; ++nf)
#pragma unroll
                for (int ks = 0; ks < 2; ++ks)
                    acc[mf][nf] = __builtin_amdgcn_mfma_f32_16x16x32_bf16(
                        af[mf][ks], bf[nf][ks], acc[mf][nf], 0, 0, 0);
        __syncthreads();
    }
#pragma unroll
    for (int mf = 0; mf < 4; ++mf)
#pragma unroll
        for (int nf = 0; nf < 4; ++nf) {
            int col = n0 + wn + nf * 16 + lr;
            float bv = 0.f;
            if (F32OUT) bv = bias[col];
#pragma unroll
            for (int i = 0; i < 4; ++i) {
                int row = m0 + wm + mf * 16 + lg * 4 + i;
                float v = acc[mf][nf][i] + bv;
                if (F32OUT)
                    ((float*)Cout)[(size_t)row * N + col] = v;
                else
                    ((short*)Cout)[(size_t)row * N + col] = f2bf(v);
            }
        }
}

// ---------------- causal flash attention ------------------------------------
// Grid: (S/64 q-tiles, B*H). 4 waves, 16 q-rows per wave (Q in regs).
// KV tile 64. Swapped QK^T (mfma(K,Q)) -> P-row lane-local, softmax via
// 2 shfl_xor. P slots pair with a transposed+permuted+XOR-swizzled V tile
// in LDS so PV needs zero shuffles.
__global__ __launch_bounds__(256) void attn_fwd(const short* __restrict__ qkv,
                                                short* __restrict__ ctx) {
    const int qt = blockIdx.x;
    const int bh = blockIdx.y;
    const int b = bh >> 4, h = bh & 15;
    const int tid = threadIdx.x;
    const int w = tid >> 6, l = tid & 63;
    const int lg = l >> 4, lr = l & 15;
    const int q0w = qt * 64 + w * 16;

    __shared__ short Ks[64 * 64];
    __shared__ short Vt[64 * 64];

    const short* base = qkv + (size_t)(b * S_) * QKVN + h * HD_;
    const short* kpg = base + D_;
    const short* vpg = base + 2 * D_;

    // Q fragments (B-operand): lane holds Q[q0w+lr][lg*8 + j + ks*32]
    short8 qf[2];
    {
        const short* g = base + (size_t)(q0w + lr) * QKVN + lg * 8;
        qf[0] = *(const short8*)g;
        qf[1] = *(const short8*)(g + 32);
    }

    float m2 = NEGBIG, lsum = 0.f;
    f32x4 cacc[4] = {};
    const float sc = 0.125f * 1.44269504089f;  // 1/sqrt(64) * log2(e)
    const int qabs = q0w + lr;

    for (int kt = 0; kt <= qt; ++kt) {
        const int kb = kt * 64;
        // --- stage K tile (global_load_lds, pre-swizzled source) ---
#pragma unroll
        for (int it = 0; it < 2; ++it) {
            int off = ((it * 4 + w) * 64 + l) * 16;
            int row = off >> 7;
            int scol = (off & 127) ^ ((row & 7) << 4);
            gload_lds16(kpg + (size_t)(kb + row) * QKVN + (scol >> 1),
                        (char*)Ks + (it * 4 + w) * 1024);
        }
        // --- stage V transposed: Vt[d][pos(kp)] with XOR swizzle ---
#pragma unroll
        for (int it = 0; it < 2; ++it) {
            int cid = it * 256 + tid;
            int r = cid >> 3, c = (cid & 7) * 8;
            short8 v = *(const short8*)(vpg + (size_t)(kb + r) * QKVN + c);
            int rem = r & 31;
            int pos = (r >> 5) * 32 + ((rem & 15) >> 2) * 8 + ((rem >> 4) & 1) * 4 + (rem & 3);
#pragma unroll
            for (int j = 0; j < 8; ++j) {
                int d = c + j;
                int sw = ((d & 7) ^ ((d >> 3) & 7)) << 3;
                Vt[d * 64 + (pos ^ sw)] = v[j];
            }
        }
        __syncthreads();

        // --- S^T = K * Q^T : lane holds S[kp = kb+f*16+lg*4+i][q = q0w+lr] ---
        f32x4 sfr[4] = {};
#pragma unroll
        for (int f = 0; f < 4; ++f)
#pragma unroll
            for (int ks = 0; ks < 2; ++ks) {
                int r = f * 16 + lr;
                short8 kf = *(const short8*)((const char*)Ks + r * 128 +
                                             ((lg * 16 + ks * 64) ^ ((r & 7) << 4)));
                sfr[f] = __builtin_amdgcn_mfma_f32_16x16x32_bf16(kf, qf[ks], sfr[f], 0, 0, 0);
            }

        // --- mask + online softmax (log2 domain) ---
        float sv[16];
        float tmax = NEGBIG;
#pragma unroll
        for (int f = 0; f < 4; ++f)
#pragma unroll
            for (int i = 0; i < 4; ++i) {
                int kpo = kb + f * 16 + lg * 4 + i;
                float s2 = (kpo <= qabs) ? sfr[f][i] * sc : NEGBIG;
                sv[f * 4 + i] = s2;
                tmax = fmaxf(tmax, s2);
            }
        tmax = fmaxf(tmax, __shfl_xor(tmax, 16));
        tmax = fmaxf(tmax, __shfl_xor(tmax, 32));
        float mnew = fmaxf(m2, tmax);
        float crs = exp2f(m2 - mnew);
        m2 = mnew;
        float psum = 0.f;
        short pb[16];
#pragma unroll
        for (int t = 0; t < 16; ++t) {
            float p = exp2f(sv[t] - mnew);
            psum += p;
            pb[t] = f2bf(p);
        }
        lsum = lsum * crs + psum;
        // rescale ctx accumulator (per-q-row factor via lane broadcast)
#pragma unroll
        for (int i = 0; i < 4; ++i) {
            float ci = __shfl(crs, lg * 4 + i);
#pragma unroll
            for (int nf = 0; nf < 4; ++nf) cacc[nf][i] *= ci;
        }
        // pack P into PV A-operand: slot (lg,j) <-> kp = ks*32 + pi(lg,j)
        short8 pa[2];
#pragma unroll
        for (int ks = 0; ks < 2; ++ks)
#pragma unroll
            for (int j = 0; j < 8; ++j)
                pa[ks][j] = pb[(2 * ks + (j >> 2)) * 4 + (j & 3)];
        // --- PV: ctx[q][d] += P * V ---
#pragma unroll
        for (int nf = 0; nf < 4; ++nf) {
            int Dd = nf * 16 + lr;
            int sw = ((Dd & 7) ^ ((Dd >> 3) & 7)) << 3;
#pragma unroll
            for (int ks = 0; ks < 2; ++ks) {
                short8 vf = *(const short8*)&Vt[Dd * 64 + ((ks * 32 + lg * 8) ^ sw)];
                cacc[nf] = __builtin_amdgcn_mfma_f32_16x16x32_bf16(pa[ks], vf, cacc[nf], 0, 0, 0);
            }
        }
        __syncthreads();
    }

    // final: full row sum, divide, store ctx as bf16 [B*S][D] (head-major cols)
    lsum += __shfl_xor(lsum, 16);
    lsum += __shfl_xor(lsum, 32);
    float inv = 1.0f / lsum;
#pragma unroll
    for (int i = 0; i < 4; ++i) {
        float li = __shfl(inv, lg * 4 + i);
        int srow = q0w + lg * 4 + i;
        short* o = ctx + (size_t)(b * S_ + srow) * D_ + h * HD_ + lr;
#pragma unroll
        for (int nf = 0; nf < 4; ++nf) o[nf * 16] = f2bf(cacc[nf][i] * li);
    }
}

// ---------------------------------------------------------------------------
extern "C" void kernel_launch(void* const* d_in, const int* in_sizes, int n_in,
                              void* d_out, int out_size, void* d_ws, size_t ws_size,
                              hipStream_t stream) {
    const float* x  = (const float*)d_in[0];
    const float* Wq = (const float*)d_in[1];
    const float* Wk = (const float*)d_in[2];
    const float* Wv = (const float*)d_in[3];
    const float* Wo = (const float*)d_in[4];
    const float* bo = (const float*)d_in[5];

    short* xb   = (short*)d_ws;                  // 4096*1024 bf16
    short* Wqkv = xb + (size_t)BS_ * D_;         // 3072*1024 bf16 (Wq|Wk|Wv rows)
    short* Wob  = Wqkv + (size_t)QKVN * D_;      // 1024*1024 bf16
    short* qkvb = Wob + (size_t)D_ * D_;         // 4096*3072 bf16
    short* ctxb = qkvb + (size_t)BS_ * QKVN;     // 4096*1024 bf16

    castk<<<1024, 256, 0, stream>>>(x, xb, BS_ * D_ / 8);
    castk<<<512, 256, 0, stream>>>(Wq, Wqkv, D_ * D_ / 8);
    castk<<<512, 256, 0, stream>>>(Wk, Wqkv + D_ * D_, D_ * D_ / 8);
    castk<<<512, 256, 0, stream>>>(Wv, Wqkv + 2 * D_ * D_, D_ * D_ / 8);
    castk<<<512, 256, 0, stream>>>(Wo, Wob, D_ * D_ / 8);

    // QKV projection: [4096,3072] = xb @ Wqkv^T
    gemm_nt<false><<<dim3((BS_ / 128) * (QKVN / 128)), 256, 0, stream>>>(
        xb, Wqkv, qkvb, nullptr, BS_, QKVN, D_);

    // causal attention -> ctx [4096,1024] bf16
    attn_fwd<<<dim3(S_ / 64, B_ * H_), 256, 0, stream>>>(qkvb, ctxb);

    // output projection: out [4096,1024] f32 = ctxb @ Wob^T + bo
    gemm_nt<true><<<dim3((BS_ / 128) * (D_ / 128)), 256, 0, stream>>>(
        ctxb, Wob, d_out, bo, BS_, D_, D_);
}

// Round 6
// 233.756 us; speedup vs baseline: 1.0795x; 1.0795x over previous
//
#include <hip/hip_runtime.h>
#include <stdint.h>

typedef __attribute__((ext_vector_type(8))) short short8;
typedef __attribute__((ext_vector_type(4))) short s16x4;
typedef __attribute__((ext_vector_type(4))) float f32x4;

#define B_ 2
#define S_ 2048
#define D_ 1024
#define H_ 16
#define HD_ 64
#define BS_ (B_ * S_)   // 4096 rows
#define QKVN (3 * D_)   // 3072 fused N
#define QKN 2048        // Q|K packed stride

#define NEGBIG (-1e30f)

__device__ __forceinline__ short f2bf(float f) {
    uint32_t u = __builtin_bit_cast(uint32_t, f);
    u = (u + 0x7FFFu + ((u >> 16) & 1u)) >> 16;
    return (short)u;
}

__device__ __forceinline__ void gload_lds16(const void* g, void* lds) {
    __builtin_amdgcn_global_load_lds(
        (const __attribute__((address_space(1))) void*)g,
        (__attribute__((address_space(3))) void*)lds, 16, 0, 0);
}

// ---------------- f32 -> bf16 cast (vectorized, grid-stride, w/ scale) ------
__global__ void castk(const float* __restrict__ s, short* __restrict__ d, int n8,
                      float scale) {
    int i = blockIdx.x * blockDim.x + threadIdx.x;
    int stride = gridDim.x * blockDim.x;
    for (; i < n8; i += stride) {
        const float* sp = s + (size_t)i * 8;
        short8 o;
#pragma unroll
        for (int j = 0; j < 8; ++j) o[j] = f2bf(sp[j] * scale);
        *(short8*)(d + (size_t)i * 8) = o;
    }
}

// ---------------- NT GEMM: C[M,N] = A[M,K] * Bt[N,K]^T ----------------------
// 128x128 tile, BK=64, 4 waves (2x2), 16x16x32 bf16 MFMA.
// MODE 1: f32 out + bias (stride N).  MODE 2: QKV-fused — Q/K cols -> qkb
// (bf16, stride 2048); V cols -> vtg (bf16 V^T with PV slot permutation
// baked along the token axis).
template <int MODE>
__global__ __launch_bounds__(256) void gemm_nt(
    const short* __restrict__ A, const short* __restrict__ Bt,
    void* __restrict__ Cout, const float* __restrict__ bias,
    short* __restrict__ vtg, int M, int N, int K) {
    __shared__ short As[128 * 64];
    __shared__ short Bs[128 * 64];
    const int tid = threadIdx.x;
    const int w = tid >> 6, l = tid & 63;
    const int lg = l >> 4, lr = l & 15;
    const int nbn = N >> 7;
    const int bm = blockIdx.x / nbn, bn = blockIdx.x % nbn;
    const int m0 = bm << 7, n0 = bn << 7;
    const int wm = (w >> 1) << 6, wn = (w & 1) << 6;

    f32x4 acc[4][4] = {};

    for (int kt = 0; kt < K; kt += 64) {
#pragma unroll
        for (int it = 0; it < 4; ++it) {
            int off = ((it * 4 + w) * 64 + l) * 16;  // byte offset in tile
            int row = off >> 7;                      // 128B per row (64 bf16)
            int scol = (off & 127) ^ ((row & 7) << 4);
            gload_lds16(A + (size_t)(m0 + row) * K + kt + (scol >> 1),
                        (char*)As + (it * 4 + w) * 1024);
            gload_lds16(Bt + (size_t)(n0 + row) * K + kt + (scol >> 1),
                        (char*)Bs + (it * 4 + w) * 1024);
        }
        __syncthreads();
        short8 af[4][2], bf[4][2];
#pragma unroll
        for (int f = 0; f < 4; ++f)
#pragma unroll
            for (int ks = 0; ks < 2; ++ks) {
                int ra = wm + f * 16 + lr;
                af[f][ks] = *(const short8*)((const char*)As + ra * 128 +
                                             ((lg * 16 + ks * 64) ^ ((ra & 7) << 4)));
                int rb = wn + f * 16 + lr;
                bf[f][ks] = *(const short8*)((const char*)Bs + rb * 128 +
                                             ((lg * 16 + ks * 64) ^ ((rb & 7) << 4)));
            }
#pragma unroll
        for (int mf = 0; mf < 4; ++mf)
#pragma unroll
            for (int nf = 0; nf < 4; ++nf)
#pragma unroll
                for (int ks = 0; ks < 2; ++ks)
                    acc[mf][nf] = __builtin_amdgcn_mfma_f32_16x16x32_bf16(
                        af[mf][ks], bf[nf][ks], acc[mf][nf], 0, 0, 0);
        __syncthreads();
    }

    if (MODE == 2 && n0 >= QKN) {
        // V columns: write permuted V^T  vtg[((b*16+h)*64+d)*2048 + tok']
#pragma unroll
        for (int mf = 0; mf < 4; ++mf)
#pragma unroll
            for (int nf = 0; nf < 4; ++nf) {
                int col = n0 + wn + nf * 16 + lr - QKN;  // 0..1023
                int hh = col >> 6, d = col & 63;
                int token = m0 + wm + mf * 16 + lg * 4;  // +i (i=0..3, token%4==0)
                int b = token >> 11, tk = token & 2047;
                int t64 = tk & ~63, rem = tk & 63;
                int r32 = rem & 31;
                int pos = (rem >> 5) * 32 + ((r32 & 15) >> 2) * 8 + ((r32 >> 4) & 1) * 4;
                s16x4 o;
#pragma unroll
                for (int i = 0; i < 4; ++i) o[i] = f2bf(acc[mf][nf][i]);
                *(s16x4*)&vtg[((size_t)(b * 16 + hh) * 64 + d) * (size_t)S_ + t64 + pos] = o;
            }
        return;
    }

#pragma unroll
    for (int mf = 0; mf < 4; ++mf)
#pragma unroll
        for (int nf = 0; nf < 4; ++nf) {
            int col = n0 + wn + nf * 16 + lr;
            float bv = 0.f;
            if (MODE == 1) bv = bias[col];
#pragma unroll
            for (int i = 0; i < 4; ++i) {
                int row = m0 + wm + mf * 16 + lg * 4 + i;
                float v = acc[mf][nf][i] + bv;
                if (MODE == 1)
                    ((float*)Cout)[(size_t)row * N + col] = v;
                else
                    ((short*)Cout)[(size_t)row * QKN + col] = f2bf(v);
            }
        }
}

// ---------------- causal flash attention ------------------------------------
// Grid: (S/64 q-tiles reversed, B*H). 4 waves, 16 q-rows per wave (Q in regs).
// KV tile 64, double-buffered K + V^T staged via global_load_lds (V^T comes
// pre-transposed+permuted from the QKV GEMM epilogue). Swapped QK^T -> P
// lane-local; PV pairs P slots with permuted V^T rows, zero shuffles.
__global__ __launch_bounds__(256) void attn_fwd(const short* __restrict__ qkb,
                                                const short* __restrict__ vtg,
                                                short* __restrict__ ctx) {
    const int qt = (S_ / 64 - 1) - blockIdx.x;  // heavy blocks first
    const int bh = blockIdx.y;
    const int b = bh >> 4, h = bh & 15;
    const int tid = threadIdx.x;
    const int w = tid >> 6, l = tid & 63;
    const int lg = l >> 4, lr = l & 15;
    const int q0w = qt * 64 + w * 16;

    __shared__ short Ks[2][64 * 64];
    __shared__ short Vt[2][64 * 64];

    const short* base = qkb + (size_t)(b * S_) * QKN + h * HD_;
    const short* kpg = base + D_;
    const short* vrow = vtg + (size_t)bh * 64 * S_;  // rows of 2048 tokens

    // Q fragments: lane holds Q[q0w+lr][lg*8 + j + ks*32]  (pre-scaled by
    // log2e/sqrt(HD) via the Wq cast)
    short8 qf[2];
    {
        const short* g = base + (size_t)(q0w + lr) * QKN + lg * 8;
        qf[0] = *(const short8*)g;
        qf[1] = *(const short8*)(g + 32);
    }

    float m2 = NEGBIG, lsum = 0.f;
    f32x4 cacc[4] = {};
    const int qabs = q0w + lr;

    // stage tile kb into buffer `buf` (K rows + V^T rows, both 128B/row,
    // pre-swizzled global source so linear LDS + XOR-swizzled reads match)
    auto stage = [&](int kb, int buf) {
#pragma unroll
        for (int it = 0; it < 2; ++it) {
            int off = ((it * 4 + w) * 64 + l) * 16;
            int row = off >> 7;
            int scol = (off & 127) ^ ((row & 7) << 4);
            gload_lds16(kpg + (size_t)(kb + row) * QKN + (scol >> 1),
                        (char*)Ks[buf] + (it * 4 + w) * 1024);
            gload_lds16(vrow + (size_t)row * S_ + kb + (scol >> 1),
                        (char*)Vt[buf] + (it * 4 + w) * 1024);
        }
    };

    stage(0, 0);
    __syncthreads();

    for (int kt = 0; kt <= qt; ++kt) {
        const int buf = kt & 1;
        if (kt < qt) stage((kt + 1) * 64, buf ^ 1);

        const char* ksb = (const char*)Ks[buf];
        const char* vtb = (const char*)Vt[buf];

        // --- S^T = K * Q^T : lane holds S[kp = f*16+lg*4+i][q = lr] ---
        f32x4 sfr[4] = {};
#pragma unroll
        for (int f = 0; f < 4; ++f)
#pragma unroll
            for (int ks = 0; ks < 2; ++ks) {
                int r = f * 16 + lr;
                short8 kf = *(const short8*)(ksb + r * 128 +
                                             ((lg * 16 + ks * 64) ^ ((r & 7) << 4)));
                sfr[f] = __builtin_amdgcn_mfma_f32_16x16x32_bf16(kf, qf[ks], sfr[f], 0, 0, 0);
            }

        // --- online softmax (log2 domain, scale pre-folded into Q) ---
        float sv[16];
        float tmax = NEGBIG;
        if (kt == qt) {  // diagonal tile: causal mask
            const int kb = kt * 64;
#pragma unroll
            for (int f = 0; f < 4; ++f)
#pragma unroll
                for (int i = 0; i < 4; ++i) {
                    int kpo = kb + f * 16 + lg * 4 + i;
                    float s2 = (kpo <= qabs) ? sfr[f][i] : NEGBIG;
                    sv[f * 4 + i] = s2;
                    tmax = fmaxf(tmax, s2);
                }
        } else {
#pragma unroll
            for (int f = 0; f < 4; ++f)
#pragma unroll
                for (int i = 0; i < 4; ++i) {
                    float s2 = sfr[f][i];
                    sv[f * 4 + i] = s2;
                    tmax = fmaxf(tmax, s2);
                }
        }
        tmax = fmaxf(tmax, __shfl_xor(tmax, 16));
        tmax = fmaxf(tmax, __shfl_xor(tmax, 32));
        // defer-max: only rescale when the running max moved by > 8 (log2)
        if (!__all(tmax - m2 <= 8.f)) {
            float mnew = fmaxf(m2, tmax);
            float crs = exp2f(m2 - mnew);
            m2 = mnew;
            lsum *= crs;
#pragma unroll
            for (int i = 0; i < 4; ++i) {
                float ci = __shfl(crs, lg * 4 + i);
#pragma unroll
                for (int nf = 0; nf < 4; ++nf) cacc[nf][i] *= ci;
            }
        }
        float psum = 0.f;
        short pb[16];
#pragma unroll
        for (int t = 0; t < 16; ++t) {
            float p = exp2f(sv[t] - m2);
            psum += p;
            pb[t] = f2bf(p);
        }
        lsum += psum;

        // pack P into PV A-operand: slot (lg,ks,j) <-> kp = 32ks+16(j>>2)+4lg+(j&3)
        short8 pa[2];
#pragma unroll
        for (int ks = 0; ks < 2; ++ks)
#pragma unroll
            for (int j = 0; j < 8; ++j)
                pa[ks][j] = pb[(2 * ks + (j >> 2)) * 4 + (j & 3)];

        // --- PV: ctx[q][d] += P * V  (V^T rows already slot-permuted) ---
#pragma unroll
        for (int nf = 0; nf < 4; ++nf) {
            int r = nf * 16 + lr;  // d
#pragma unroll
            for (int ks = 0; ks < 2; ++ks) {
                short8 vf = *(const short8*)(vtb + r * 128 +
                                             ((ks * 64 + lg * 16) ^ ((r & 7) << 4)));
                cacc[nf] = __builtin_amdgcn_mfma_f32_16x16x32_bf16(pa[ks], vf, cacc[nf], 0, 0, 0);
            }
        }
        __syncthreads();
    }

    // final: full row sum, divide, store ctx as bf16 [B*S][D]
    lsum += __shfl_xor(lsum, 16);
    lsum += __shfl_xor(lsum, 32);
    float inv = 1.0f / lsum;
#pragma unroll
    for (int i = 0; i < 4; ++i) {
        float li = __shfl(inv, lg * 4 + i);
        int srow = q0w + lg * 4 + i;
        short* o = ctx + (size_t)(b * S_ + srow) * D_ + h * HD_ + lr;
#pragma unroll
        for (int nf = 0; nf < 4; ++nf) o[nf * 16] = f2bf(cacc[nf][i] * li);
    }
}

// ---------------------------------------------------------------------------
extern "C" void kernel_launch(void* const* d_in, const int* in_sizes, int n_in,
                              void* d_out, int out_size, void* d_ws, size_t ws_size,
                              hipStream_t stream) {
    const float* x  = (const float*)d_in[0];
    const float* Wq = (const float*)d_in[1];
    const float* Wk = (const float*)d_in[2];
    const float* Wv = (const float*)d_in[3];
    const float* Wo = (const float*)d_in[4];
    const float* bo = (const float*)d_in[5];

    short* xb   = (short*)d_ws;                  // 4096*1024 bf16   (8 MB)
    short* Wqkv = xb + (size_t)BS_ * D_;         // 3072*1024 bf16   (6 MB)
    short* Wob  = Wqkv + (size_t)QKVN * D_;      // 1024*1024 bf16   (2 MB)
    short* qkb  = Wob + (size_t)D_ * D_;         // 4096*2048 bf16  (16 MB) Q|K
    short* ctxb = qkb + (size_t)BS_ * QKN;       // 4096*1024 bf16   (8 MB)
    short* vtg  = ctxb + (size_t)BS_ * D_;       // 2*16*64*2048 bf16 (8 MB) V^T

    const float qscale = 0.125f * 1.44269504089f;  // 1/sqrt(64) * log2(e)
    castk<<<1024, 256, 0, stream>>>(x, xb, BS_ * D_ / 8, 1.0f);
    castk<<<512, 256, 0, stream>>>(Wq, Wqkv, D_ * D_ / 8, qscale);
    castk<<<512, 256, 0, stream>>>(Wk, Wqkv + D_ * D_, D_ * D_ / 8, 1.0f);
    castk<<<512, 256, 0, stream>>>(Wv, Wqkv + 2 * D_ * D_, D_ * D_ / 8, 1.0f);
    castk<<<512, 256, 0, stream>>>(Wo, Wob, D_ * D_ / 8, 1.0f);

    // QKV projection: Q/K -> qkb [4096][2048]; V -> vtg (V^T, permuted)
    gemm_nt<2><<<dim3((BS_ / 128) * (QKVN / 128)), 256, 0, stream>>>(
        xb, Wqkv, qkb, nullptr, vtg, BS_, QKVN, D_);

    // causal attention -> ctx [4096,1024] bf16
    attn_fwd<<<dim3(S_ / 64, B_ * H_), 256, 0, stream>>>(qkb, vtg, ctxb);

    // output projection: out [4096,1024] f32 = ctxb @ Wob^T + bo
    gemm_nt<1><<<dim3((BS_ / 128) * (D_ / 128)), 256, 0, stream>>>(
        ctxb, Wob, d_out, bo, nullptr, BS_, D_, D_);
}

// Round 8
// 217.225 us; speedup vs baseline: 1.1617x; 1.0761x over previous
//
#include <hip/hip_runtime.h>
#include <stdint.h>

typedef __attribute__((ext_vector_type(8))) short short8;
typedef __attribute__((ext_vector_type(4))) short s16x4;
typedef __attribute__((ext_vector_type(4))) float f32x4;
typedef __attribute__((ext_vector_type(4))) uint32_t u32x4;

#define B_ 2
#define S_ 2048
#define D_ 1024
#define H_ 16
#define HD_ 64
#define BS_ (B_ * S_)   // 4096 rows
#define QKVN (3 * D_)   // 3072 fused N
#define QKN 2048        // Q|K packed stride
#define XN8 (BS_ * D_ / 8)   // 524288
#define WN8 (D_ * D_ / 8)    // 131072

#define NEGBIG (-1e30f)

__device__ __forceinline__ short f2bf(float f) {
    uint32_t u = __builtin_bit_cast(uint32_t, f);
    u = (u + 0x7FFFu + ((u >> 16) & 1u)) >> 16;
    return (short)u;
}

__device__ __forceinline__ uint32_t cvtpk_bf16(float lo, float hi) {
    uint32_t r;
    asm("v_cvt_pk_bf16_f32 %0, %1, %2" : "=v"(r) : "v"(lo), "v"(hi));
    return r;
}

__device__ __forceinline__ void gload_lds16(const void* g, void* lds) {
    __builtin_amdgcn_global_load_lds(
        (const __attribute__((address_space(1))) void*)g,
        (__attribute__((address_space(3))) void*)lds, 16, 0, 0);
}

// ---------------- fused f32 -> bf16 cast for x|Wq|Wk|Wv|Wo ------------------
// dst = d_ws base: regions xb | Wqkv(q,k,v) | Wob are contiguous.
__global__ void castall(const float* __restrict__ x, const float* __restrict__ Wq,
                        const float* __restrict__ Wk, const float* __restrict__ Wv,
                        const float* __restrict__ Wo, short* __restrict__ dst,
                        float qs) {
    int i = blockIdx.x * blockDim.x + threadIdx.x;
    int stride = gridDim.x * blockDim.x;
    const int total = XN8 + 4 * WN8;
    for (; i < total; i += stride) {
        const float* s;
        int loc;
        float sc = 1.f;
        if (i < XN8) {
            s = x; loc = i;
        } else {
            int r = i - XN8;
            int wi = r >> 17;        // / WN8 (2^17)
            loc = r & (WN8 - 1);
            s = (wi == 0) ? Wq : (wi == 1) ? Wk : (wi == 2) ? Wv : Wo;
            if (wi == 0) sc = qs;
        }
        const float* sp = s + (size_t)loc * 8;
        short8 o;
#pragma unroll
        for (int j = 0; j < 8; ++j) o[j] = f2bf(sp[j] * sc);
        *(short8*)(dst + (size_t)i * 8) = o;
    }
}

// ---------------- NT GEMM: C[M,N] = A[M,K] * Bt[N,K]^T ----------------------
// 128x128 tile, BK=64, 4 waves (2x2), 16x16x32 bf16 MFMA.
// MODE 1: f32 out + bias (stride N).  MODE 2: QKV-fused — Q/K cols -> qkb
// (bf16, stride 2048); V cols -> vtg (bf16 V^T with PV slot permutation
// baked along the token axis).
template <int MODE>
__global__ __launch_bounds__(256) void gemm_nt(
    const short* __restrict__ A, const short* __restrict__ Bt,
    void* __restrict__ Cout, const float* __restrict__ bias,
    short* __restrict__ vtg, int M, int N, int K) {
    __shared__ short As[128 * 64];
    __shared__ short Bs[128 * 64];
    const int tid = threadIdx.x;
    const int w = tid >> 6, l = tid & 63;
    const int lg = l >> 4, lr = l & 15;
    const int nbn = N >> 7;
    const int bm = blockIdx.x / nbn, bn = blockIdx.x % nbn;
    const int m0 = bm << 7, n0 = bn << 7;
    const int wm = (w >> 1) << 6, wn = (w & 1) << 6;

    f32x4 acc[4][4] = {};

    for (int kt = 0; kt < K; kt += 64) {
#pragma unroll
        for (int it = 0; it < 4; ++it) {
            int off = ((it * 4 + w) * 64 + l) * 16;  // byte offset in tile
            int row = off >> 7;                      // 128B per row (64 bf16)
            int scol = (off & 127) ^ ((row & 7) << 4);
            gload_lds16(A + (size_t)(m0 + row) * K + kt + (scol >> 1),
                        (char*)As + (it * 4 + w) * 1024);
            gload_lds16(Bt + (size_t)(n0 + row) * K + kt + (scol >> 1),
                        (char*)Bs + (it * 4 + w) * 1024);
        }
        __syncthreads();
        short8 af[4][2], bf[4][2];
#pragma unroll
        for (int f = 0; f < 4; ++f)
#pragma unroll
            for (int ks = 0; ks < 2; ++ks) {
                int ra = wm + f * 16 + lr;
                af[f][ks] = *(const short8*)((const char*)As + ra * 128 +
                                             ((lg * 16 + ks * 64) ^ ((ra & 7) << 4)));
                int rb = wn + f * 16 + lr;
                bf[f][ks] = *(const short8*)((const char*)Bs + rb * 128 +
                                             ((lg * 16 + ks * 64) ^ ((rb & 7) << 4)));
            }
#pragma unroll
        for (int mf = 0; mf < 4; ++mf)
#pragma unroll
            for (int nf = 0; nf < 4; ++nf)
#pragma unroll
                for (int ks = 0; ks < 2; ++ks)
                    acc[mf][nf] = __builtin_amdgcn_mfma_f32_16x16x32_bf16(
                        af[mf][ks], bf[nf][ks], acc[mf][nf], 0, 0, 0);
        __syncthreads();
    }

    if (MODE == 2 && n0 >= QKN) {
        // V columns: write permuted V^T  vtg[((b*16+h)*64+d)*2048 + tok']
#pragma unroll
        for (int mf = 0; mf < 4; ++mf)
#pragma unroll
            for (int nf = 0; nf < 4; ++nf) {
                int col = n0 + wn + nf * 16 + lr - QKN;  // 0..1023
                int hh = col >> 6, d = col & 63;
                int token = m0 + wm + mf * 16 + lg * 4;  // +i (i=0..3, token%4==0)
                int b = token >> 11, tk = token & 2047;
                int t64 = tk & ~63, rem = tk & 63;
                int r32 = rem & 31;
                int pos = (rem >> 5) * 32 + ((r32 & 15) >> 2) * 8 + ((r32 >> 4) & 1) * 4;
                s16x4 o;
#pragma unroll
                for (int i = 0; i < 4; ++i) o[i] = f2bf(acc[mf][nf][i]);
                *(s16x4*)&vtg[((size_t)(b * 16 + hh) * 64 + d) * (size_t)S_ + t64 + pos] = o;
            }
        return;
    }

#pragma unroll
    for (int mf = 0; mf < 4; ++mf)
#pragma unroll
        for (int nf = 0; nf < 4; ++nf) {
            int col = n0 + wn + nf * 16 + lr;
            float bv = 0.f;
            if (MODE == 1) bv = bias[col];
#pragma unroll
            for (int i = 0; i < 4; ++i) {
                int row = m0 + wm + mf * 16 + lg * 4 + i;
                float v = acc[mf][nf][i] + bv;
                if (MODE == 1)
                    ((float*)Cout)[(size_t)row * N + col] = v;
                else
                    ((short*)Cout)[(size_t)row * QKN + col] = f2bf(v);
            }
        }
}

// ---------------- causal flash attention ------------------------------------
// Grid: (S/64 q-tiles reversed, B*H). 4 waves, 16 q-rows per wave (Q in regs).
// KV tile 64, double-buffered K + V^T staged via global_load_lds (V^T comes
// pre-transposed+permuted from the QKV GEMM epilogue). Swapped QK^T -> P
// lane-local; PV pairs P slots with permuted V^T rows, zero shuffles.
// Softmax: lane-local defer-max common path (no cross-lane ops), cvt_pk
// bf16 packing, explicit max/sum trees.
__global__ __launch_bounds__(256) void attn_fwd(const short* __restrict__ qkb,
                                                const short* __restrict__ vtg,
                                                short* __restrict__ ctx) {
    const int qt = (S_ / 64 - 1) - blockIdx.x;  // heavy blocks first
    const int bh = blockIdx.y;
    const int b = bh >> 4, h = bh & 15;
    const int tid = threadIdx.x;
    const int w = tid >> 6, l = tid & 63;
    const int lg = l >> 4, lr = l & 15;
    const int q0w = qt * 64 + w * 16;

    __shared__ short Ks[2][64 * 64];
    __shared__ short Vt[2][64 * 64];

    const short* base = qkb + (size_t)(b * S_) * QKN + h * HD_;
    const short* kpg = base + D_;
    const short* vrow = vtg + (size_t)bh * 64 * S_;  // rows of 2048 tokens

    // Q fragments: lane holds Q[q0w+lr][lg*8 + j + ks*32]  (pre-scaled by
    // log2e/sqrt(HD) via the Wq cast)
    short8 qf[2];
    {
        const short* g = base + (size_t)(q0w + lr) * QKN + lg * 8;
        qf[0] = *(const short8*)g;
        qf[1] = *(const short8*)(g + 32);
    }

    // strength-reduced staging pointers (advance by fixed stride per tile)
    int off0 = (w * 64 + l) * 16, off1 = ((4 + w) * 64 + l) * 16;
    int row0 = off0 >> 7, row1 = off1 >> 7;
    int sc0 = (off0 & 127) ^ ((row0 & 7) << 4);
    int sc1 = (off1 & 127) ^ ((row1 & 7) << 4);
    const short* kA = kpg + (size_t)row0 * QKN + (sc0 >> 1);
    const short* kB = kpg + (size_t)row1 * QKN + (sc1 >> 1);
    const short* vA = vrow + (size_t)row0 * S_ + (sc0 >> 1);
    const short* vB = vrow + (size_t)row1 * S_ + (sc1 >> 1);
    char* ldsKA[2] = {(char*)Ks[0] + w * 1024, (char*)Ks[1] + w * 1024};
    char* ldsKB[2] = {(char*)Ks[0] + (4 + w) * 1024, (char*)Ks[1] + (4 + w) * 1024};
    char* ldsVA[2] = {(char*)Vt[0] + w * 1024, (char*)Vt[1] + w * 1024};
    char* ldsVB[2] = {(char*)Vt[0] + (4 + w) * 1024, (char*)Vt[1] + (4 + w) * 1024};

    auto stage = [&](int buf) {
        gload_lds16(kA, ldsKA[buf]);
        gload_lds16(kB, ldsKB[buf]);
        gload_lds16(vA, ldsVA[buf]);
        gload_lds16(vB, ldsVB[buf]);
        kA += 64 * QKN; kB += 64 * QKN; vA += 64; vB += 64;
    };

    float m2 = NEGBIG, lsum = 0.f;
    f32x4 cacc[4] = {};
    const int qabs = q0w + lr;

    stage(0);
    __syncthreads();

    for (int kt = 0; kt <= qt; ++kt) {
        const int buf = kt & 1;
        if (kt < qt) stage(buf ^ 1);

        const char* ksb = (const char*)Ks[buf];
        const char* vtb = (const char*)Vt[buf];

        // --- S^T = K * Q^T : lane holds S[kp = f*16+lg*4+i][q = lr] ---
        f32x4 sfr[4] = {};
#pragma unroll
        for (int f = 0; f < 4; ++f)
#pragma unroll
            for (int ks = 0; ks < 2; ++ks) {
                int r = f * 16 + lr;
                short8 kf = *(const short8*)(ksb + r * 128 +
                                             ((lg * 16 + ks * 64) ^ ((r & 7) << 4)));
                sfr[f] = __builtin_amdgcn_mfma_f32_16x16x32_bf16(kf, qf[ks], sfr[f], 0, 0, 0);
            }

        // --- mask into p[], lane-local max tree ---
        float p[16];
        if (kt == qt) {  // diagonal tile: causal mask
            const int kb = kt * 64;
#pragma unroll
            for (int f = 0; f < 4; ++f)
#pragma unroll
                for (int i = 0; i < 4; ++i) {
                    int kpo = kb + f * 16 + lg * 4 + i;
                    p[f * 4 + i] = (kpo <= qabs) ? sfr[f][i] : NEGBIG;
                }
        } else {
#pragma unroll
            for (int f = 0; f < 4; ++f)
#pragma unroll
                for (int i = 0; i < 4; ++i) p[f * 4 + i] = sfr[f][i];
        }
        float mx01 = fmaxf(fmaxf(p[0], p[1]), fmaxf(p[2], p[3]));
        float mx23 = fmaxf(fmaxf(p[4], p[5]), fmaxf(p[6], p[7]));
        float mx45 = fmaxf(fmaxf(p[8], p[9]), fmaxf(p[10], p[11]));
        float mx67 = fmaxf(fmaxf(p[12], p[13]), fmaxf(p[14], p[15]));
        float tmax = fmaxf(fmaxf(mx01, mx23), fmaxf(mx45, mx67));

        // defer-max: __all reduces across the wave; no shuffles on common path
        if (!__all(tmax - m2 <= 8.f)) {
            float rmax = fmaxf(tmax, __shfl_xor(tmax, 16));
            rmax = fmaxf(rmax, __shfl_xor(rmax, 32));
            float mnew = fmaxf(m2, rmax);
            float crs = exp2f(m2 - mnew);
            m2 = mnew;
            lsum *= crs;
#pragma unroll
            for (int i = 0; i < 4; ++i) {
                float ci = __shfl(crs, lg * 4 + i);
#pragma unroll
                for (int nf = 0; nf < 4; ++nf) cacc[nf][i] *= ci;
            }
        }
#pragma unroll
        for (int t = 0; t < 16; ++t) p[t] = exp2f(p[t] - m2);
        float s0 = (p[0] + p[1]) + (p[2] + p[3]);
        float s1 = (p[4] + p[5]) + (p[6] + p[7]);
        float s2 = (p[8] + p[9]) + (p[10] + p[11]);
        float s3 = (p[12] + p[13]) + (p[14] + p[15]);
        lsum += (s0 + s1) + (s2 + s3);

        // pack P into PV A-operand via v_cvt_pk_bf16_f32:
        // word wd of pa[ks] holds elements t=(2ks+(wd>>1))*4+(wd&1)*2, t+1
        short8 pa[2];
#pragma unroll
        for (int ks = 0; ks < 2; ++ks) {
            u32x4 pw;
#pragma unroll
            for (int wd = 0; wd < 4; ++wd) {
                int tb = (2 * ks + (wd >> 1)) * 4 + (wd & 1) * 2;
                pw[wd] = cvtpk_bf16(p[tb], p[tb + 1]);
            }
            pa[ks] = __builtin_bit_cast(short8, pw);
        }

        // --- PV: ctx[q][d] += P * V  (V^T rows already slot-permuted) ---
#pragma unroll
        for (int nf = 0; nf < 4; ++nf) {
            int r = nf * 16 + lr;  // d
#pragma unroll
            for (int ks = 0; ks < 2; ++ks) {
                short8 vf = *(const short8*)(vtb + r * 128 +
                                             ((ks * 64 + lg * 16) ^ ((r & 7) << 4)));
                cacc[nf] = __builtin_amdgcn_mfma_f32_16x16x32_bf16(pa[ks], vf, cacc[nf], 0, 0, 0);
            }
        }
        __syncthreads();
    }

    // final: full row sum, divide, store ctx as bf16 [B*S][D]
    lsum += __shfl_xor(lsum, 16);
    lsum += __shfl_xor(lsum, 32);
    float inv = 1.0f / lsum;
#pragma unroll
    for (int i = 0; i < 4; ++i) {
        float li = __shfl(inv, lg * 4 + i);
        int srow = q0w + lg * 4 + i;
        short* o = ctx + (size_t)(b * S_ + srow) * D_ + h * HD_ + lr;
#pragma unroll
        for (int nf = 0; nf < 4; ++nf) o[nf * 16] = f2bf(cacc[nf][i] * li);
    }
}

// ---------------------------------------------------------------------------
extern "C" void kernel_launch(void* const* d_in, const int* in_sizes, int n_in,
                              void* d_out, int out_size, void* d_ws, size_t ws_size,
                              hipStream_t stream) {
    const float* x  = (const float*)d_in[0];
    const float* Wq = (const float*)d_in[1];
    const float* Wk = (const float*)d_in[2];
    const float* Wv = (const float*)d_in[3];
    const float* Wo = (const float*)d_in[4];
    const float* bo = (const float*)d_in[5];

    short* xb   = (short*)d_ws;                  // 4096*1024 bf16   (8 MB)
    short* Wqkv = xb + (size_t)BS_ * D_;         // 3072*1024 bf16   (6 MB)
    short* Wob  = Wqkv + (size_t)QKVN * D_;      // 1024*1024 bf16   (2 MB)
    short* qkb  = Wob + (size_t)D_ * D_;         // 4096*2048 bf16  (16 MB) Q|K
    short* ctxb = qkb + (size_t)BS_ * QKN;       // 4096*1024 bf16   (8 MB)
    short* vtg  = ctxb + (size_t)BS_ * D_;       // 2*16*64*2048 bf16 (8 MB) V^T

    const float qscale = 0.125f * 1.44269504089f;  // 1/sqrt(64) * log2(e)
    castall<<<2048, 256, 0, stream>>>(x, Wq, Wk, Wv, Wo, (short*)d_ws, qscale);

    // QKV projection: Q/K -> qkb [4096][2048]; V -> vtg (V^T, permuted)
    gemm_nt<2><<<dim3((BS_ / 128) * (QKVN / 128)), 256, 0, stream>>>(
        xb, Wqkv, qkb, nullptr, vtg, BS_, QKVN, D_);

    // causal attention -> ctx [4096,1024] bf16
    attn_fwd<<<dim3(S_ / 64, B_ * H_), 256, 0, stream>>>(qkb, vtg, ctxb);

    // output projection: out [4096,1024] f32 = ctxb @ Wob^T + bo
    gemm_nt<1><<<dim3((BS_ / 128) * (D_ / 128)), 256, 0, stream>>>(
        ctxb, Wob, d_out, bo, nullptr, BS_, D_, D_);
}

// Round 11
// 187.701 us; speedup vs baseline: 1.3444x; 1.1573x over previous
//
#include <hip/hip_runtime.h>
#include <stdint.h>

typedef __attribute__((ext_vector_type(8))) short short8;
typedef __attribute__((ext_vector_type(4))) short s16x4;
typedef __attribute__((ext_vector_type(4))) float f32x4;
typedef __attribute__((ext_vector_type(4))) uint32_t u32x4;

#define B_ 2
#define S_ 2048
#define D_ 1024
#define H_ 16
#define HD_ 64
#define BS_ (B_ * S_)   // 4096 rows
#define QKVN (3 * D_)   // 3072 fused N
#define QKN 2048        // Q|K packed stride
#define XN8 (BS_ * D_ / 8)   // 524288
#define WN8 (D_ * D_ / 8)    // 131072

#define NEGBIG (-1e30f)

__device__ __forceinline__ short f2bf(float f) {
    uint32_t u = __builtin_bit_cast(uint32_t, f);
    u = (u + 0x7FFFu + ((u >> 16) & 1u)) >> 16;
    return (short)u;
}

__device__ __forceinline__ uint32_t cvtpk_bf16(float lo, float hi) {
    uint32_t r;
    asm("v_cvt_pk_bf16_f32 %0, %1, %2" : "=v"(r) : "v"(lo), "v"(hi));
    return r;
}

__device__ __forceinline__ float vexp2(float x) {
    float r;
    asm("v_exp_f32 %0, %1" : "=v"(r) : "v"(x));
    return r;
}

__device__ __forceinline__ void gload_lds16(const void* g, void* lds) {
    __builtin_amdgcn_global_load_lds(
        (const __attribute__((address_space(1))) void*)g,
        (__attribute__((address_space(3))) void*)lds, 16, 0, 0);
}

// ---------------- fused f32 -> bf16 cast for x|Wq|Wk|Wv|Wo ------------------
__global__ void castall(const float* __restrict__ x, const float* __restrict__ Wq,
                        const float* __restrict__ Wk, const float* __restrict__ Wv,
                        const float* __restrict__ Wo, short* __restrict__ dst,
                        float qs) {
    int i = blockIdx.x * blockDim.x + threadIdx.x;
    int stride = gridDim.x * blockDim.x;
    const int total = XN8 + 4 * WN8;
    for (; i < total; i += stride) {
        const float* s;
        int loc;
        float sc = 1.f;
        if (i < XN8) {
            s = x; loc = i;
        } else {
            int r = i - XN8;
            int wi = r >> 17;
            loc = r & (WN8 - 1);
            s = (wi == 0) ? Wq : (wi == 1) ? Wk : (wi == 2) ? Wv : Wo;
            if (wi == 0) sc = qs;
        }
        const float* sp = s + (size_t)loc * 8;
        short8 o;
#pragma unroll
        for (int j = 0; j < 8; ++j) o[j] = f2bf(sp[j] * sc);
        *(short8*)(dst + (size_t)i * 8) = o;
    }
}

// ---------------- NT GEMM: C[M,N] = A[M,K] * Bt[N,K]^T ----------------------
template <int MODE>
__global__ __launch_bounds__(256) void gemm_nt(
    const short* __restrict__ A, const short* __restrict__ Bt,
    void* __restrict__ Cout, const float* __restrict__ bias,
    short* __restrict__ vtg, int M, int N, int K) {
    __shared__ short As[128 * 64];
    __shared__ short Bs[128 * 64];
    const int tid = threadIdx.x;
    const int w = tid >> 6, l = tid & 63;
    const int lg = l >> 4, lr = l & 15;
    const int nbn = N >> 7;
    const int bm = blockIdx.x / nbn, bn = blockIdx.x % nbn;
    const int m0 = bm << 7, n0 = bn << 7;
    const int wm = (w >> 1) << 6, wn = (w & 1) << 6;

    f32x4 acc[4][4] = {};

    for (int kt = 0; kt < K; kt += 64) {
#pragma unroll
        for (int it = 0; it < 4; ++it) {
            int off = ((it * 4 + w) * 64 + l) * 16;
            int row = off >> 7;
            int scol = (off & 127) ^ ((row & 7) << 4);
            gload_lds16(A + (size_t)(m0 + row) * K + kt + (scol >> 1),
                        (char*)As + (it * 4 + w) * 1024);
            gload_lds16(Bt + (size_t)(n0 + row) * K + kt + (scol >> 1),
                        (char*)Bs + (it * 4 + w) * 1024);
        }
        __syncthreads();
        short8 af[4][2], bf[4][2];
#pragma unroll
        for (int f = 0; f < 4; ++f)
#pragma unroll
            for (int ks = 0; ks < 2; ++ks) {
                int ra = wm + f * 16 + lr;
                af[f][ks] = *(const short8*)((const char*)As + ra * 128 +
                                             ((lg * 16 + ks * 64) ^ ((ra & 7) << 4)));
                int rb = wn + f * 16 + lr;
                bf[f][ks] = *(const short8*)((const char*)Bs + rb * 128 +
                                             ((lg * 16 + ks * 64) ^ ((rb & 7) << 4)));
            }
#pragma unroll
        for (int mf = 0; mf < 4; ++mf)
#pragma unroll
            for (int nf = 0; nf < 4; ++nf)
#pragma unroll
                for (int ks = 0; ks < 2; ++ks)
                    acc[mf][nf] = __builtin_amdgcn_mfma_f32_16x16x32_bf16(
                        af[mf][ks], bf[nf][ks], acc[mf][nf], 0, 0, 0);
        __syncthreads();
    }

    if (MODE == 2 && n0 >= QKN) {
#pragma unroll
        for (int mf = 0; mf < 4; ++mf)
#pragma unroll
            for (int nf = 0; nf < 4; ++nf) {
                int col = n0 + wn + nf * 16 + lr - QKN;
                int hh = col >> 6, d = col & 63;
                int token = m0 + wm + mf * 16 + lg * 4;
                int b = token >> 11, tk = token & 2047;
                int t64 = tk & ~63, rem = tk & 63;
                int r32 = rem & 31;
                int pos = (rem >> 5) * 32 + ((r32 & 15) >> 2) * 8 + ((r32 >> 4) & 1) * 4;
                s16x4 o;
#pragma unroll
                for (int i = 0; i < 4; ++i) o[i] = f2bf(acc[mf][nf][i]);
                *(s16x4*)&vtg[((size_t)(b * 16 + hh) * 64 + d) * (size_t)S_ + t64 + pos] = o;
            }
        return;
    }

#pragma unroll
    for (int mf = 0; mf < 4; ++mf)
#pragma unroll
        for (int nf = 0; nf < 4; ++nf) {
            int col = n0 + wn + nf * 16 + lr;
            float bv = 0.f;
            if (MODE == 1) bv = bias[col];
#pragma unroll
            for (int i = 0; i < 4; ++i) {
                int row = m0 + wm + mf * 16 + lg * 4 + i;
                float v = acc[mf][nf][i] + bv;
                if (MODE == 1)
                    ((float*)Cout)[(size_t)row * N + col] = v;
                else
                    ((short*)Cout)[(size_t)row * QKN + col] = f2bf(v);
            }
        }
}

// ---------------- causal flash attention (paired q-tiles) -------------------
// Grid (S/128, B*H). Block bx handles q-tiles {31-bx (H), bx (L)} — 33
// iter-units each: perfect triangle balance. One k-loop stages each K/V tile
// once; LDS fragments are read once and feed BOTH tiles' MFMAs. Flat LDS +
// hoisted per-lane base offsets (immediate-offset ds_reads). Raw v_exp_f32.
__global__ __launch_bounds__(256) void attn_fwd(const short* __restrict__ qkb,
                                                const short* __restrict__ vtg,
                                                short* __restrict__ ctx) {
    const int bx = blockIdx.x;                 // 0..15
    const int qtH = (S_ / 64 - 1) - bx;        // 31-bx (heavy)
    const int qtL = bx;                        // light
    const int bh = blockIdx.y;
    const int b = bh >> 4, h = bh & 15;
    const int tid = threadIdx.x;
    const int w = tid >> 6, l = tid & 63;
    const int lg = l >> 4, lr = l & 15;

    __shared__ __align__(16) char lds[32768];  // [buf:16K][ K:8K | V:8K ]

    const short* base = qkb + (size_t)(b * S_) * QKN + h * HD_;
    const short* kpg = base + D_;
    const short* vrow = vtg + (size_t)bh * 64 * S_;

    short8 qfH[2], qfL[2];
    {
        const short* g = base + (size_t)(qtH * 64 + w * 16 + lr) * QKN + lg * 8;
        qfH[0] = *(const short8*)g;
        qfH[1] = *(const short8*)(g + 32);
        const short* g2 = base + (size_t)(qtL * 64 + w * 16 + lr) * QKN + lg * 8;
        qfL[0] = *(const short8*)g2;
        qfL[1] = *(const short8*)(g2 + 32);
    }

    // staging lane constants (pre-swizzled global sources, linear LDS dest)
    int off0 = (w * 64 + l) * 16, off1 = ((4 + w) * 64 + l) * 16;
    int row0 = off0 >> 7, row1 = off1 >> 7;
    int sc0 = (off0 & 127) ^ ((row0 & 7) << 4);
    int sc1 = (off1 & 127) ^ ((row1 & 7) << 4);
    const short* kA = kpg + (size_t)row0 * QKN + (sc0 >> 1);
    const short* kB = kpg + (size_t)row1 * QKN + (sc1 >> 1);
    const short* vA = vrow + (size_t)row0 * S_ + (sc0 >> 1);
    const short* vB = vrow + (size_t)row1 * S_ + (sc1 >> 1);
    const int dK0 = w * 1024, dK1 = (4 + w) * 1024;

    auto stage = [&](int buf) {
        char* p = lds + (buf << 14);
        gload_lds16(kA, p + dK0);
        gload_lds16(kB, p + dK1);
        gload_lds16(vA, p + 8192 + dK0);
        gload_lds16(vB, p + 8192 + dK1);
        kA += 64 * QKN; kB += 64 * QKN; vA += 64; vB += 64;
    };

    // hoisted LDS read base offsets (per-lane, loop-invariant)
    const int xorp = (lr & 7) << 4;
    const int ka0 = lr * 128 + ((lg * 16) ^ xorp);
    const int ka1 = lr * 128 + ((lg * 16 + 64) ^ xorp);
    const int va0 = 8192 + ka0;
    const int va1 = 8192 + ka1;

    float mH = NEGBIG, lsH = 0.f, mL = NEGBIG, lsL = 0.f;
    f32x4 caccH[4] = {}, caccL[4] = {};
    const int qrow = w * 16 + lr;
    const int qabsH = qtH * 64 + qrow;
    const int qabsL = qtL * 64 + qrow;

    stage(0);
    __syncthreads();

    for (int kt = 0; kt <= qtH; ++kt) {
        const int buf = kt & 1;
        if (kt < qtH) stage(buf ^ 1);
        const char* bb = lds + (buf << 14);
        const bool doL = (kt <= qtL);

        // --- K fragments read ONCE, feed both tiles ---
        short8 kf[4][2];
#pragma unroll
        for (int f = 0; f < 4; ++f) {
            kf[f][0] = *(const short8*)(bb + ka0 + f * 2048);
            kf[f][1] = *(const short8*)(bb + ka1 + f * 2048);
        }
        f32x4 sH[4] = {};
#pragma unroll
        for (int f = 0; f < 4; ++f) {
            sH[f] = __builtin_amdgcn_mfma_f32_16x16x32_bf16(kf[f][0], qfH[0], sH[f], 0, 0, 0);
            sH[f] = __builtin_amdgcn_mfma_f32_16x16x32_bf16(kf[f][1], qfH[1], sH[f], 0, 0, 0);
        }
        f32x4 sL[4] = {};
        if (doL) {
#pragma unroll
            for (int f = 0; f < 4; ++f) {
                sL[f] = __builtin_amdgcn_mfma_f32_16x16x32_bf16(kf[f][0], qfL[0], sL[f], 0, 0, 0);
                sL[f] = __builtin_amdgcn_mfma_f32_16x16x32_bf16(kf[f][1], qfL[1], sL[f], 0, 0, 0);
            }
        }
        // --- V fragments read ONCE, feed both tiles ---
        short8 vf[4][2];
#pragma unroll
        for (int nf = 0; nf < 4; ++nf) {
            vf[nf][0] = *(const short8*)(bb + va0 + nf * 2048);
            vf[nf][1] = *(const short8*)(bb + va1 + nf * 2048);
        }

        auto smpv = [&](f32x4(&sfr)[4], float& m2, float& lsum, f32x4(&cacc)[4],
                        int qabs, bool diag) {
            float p[16];
            if (diag) {
                int rel = qabs - kt * 64;
#pragma unroll
                for (int f = 0; f < 4; ++f)
#pragma unroll
                    for (int i = 0; i < 4; ++i)
                        p[f * 4 + i] = (f * 16 + lg * 4 + i <= rel) ? sfr[f][i] : NEGBIG;
            } else {
#pragma unroll
                for (int f = 0; f < 4; ++f)
#pragma unroll
                    for (int i = 0; i < 4; ++i) p[f * 4 + i] = sfr[f][i];
            }
            float t0 = fmaxf(fmaxf(p[0], p[1]), fmaxf(p[2], p[3]));
            float t1 = fmaxf(fmaxf(p[4], p[5]), fmaxf(p[6], p[7]));
            float t2 = fmaxf(fmaxf(p[8], p[9]), fmaxf(p[10], p[11]));
            float t3 = fmaxf(fmaxf(p[12], p[13]), fmaxf(p[14], p[15]));
            float tmax = fmaxf(fmaxf(t0, t1), fmaxf(t2, t3));
            if (!__all(tmax - m2 <= 8.f)) {
                float rmax = fmaxf(tmax, __shfl_xor(tmax, 16));
                rmax = fmaxf(rmax, __shfl_xor(rmax, 32));
                float mnew = fmaxf(m2, rmax);
                float crs = vexp2(m2 - mnew);
                m2 = mnew;
                lsum *= crs;
#pragma unroll
                for (int i = 0; i < 4; ++i) {
                    float ci = __shfl(crs, lg * 4 + i);
#pragma unroll
                    for (int nf = 0; nf < 4; ++nf) cacc[nf][i] *= ci;
                }
            }
#pragma unroll
            for (int t = 0; t < 16; ++t) p[t] = vexp2(p[t] - m2);
            float s0 = (p[0] + p[1]) + (p[2] + p[3]);
            float s1 = (p[4] + p[5]) + (p[6] + p[7]);
            float s2 = (p[8] + p[9]) + (p[10] + p[11]);
            float s3 = (p[12] + p[13]) + (p[14] + p[15]);
            lsum += (s0 + s1) + (s2 + s3);
            short8 pa[2];
#pragma unroll
            for (int ks = 0; ks < 2; ++ks) {
                u32x4 pw;
#pragma unroll
                for (int wd = 0; wd < 4; ++wd) {
                    int tb = (2 * ks + (wd >> 1)) * 4 + (wd & 1) * 2;
                    pw[wd] = cvtpk_bf16(p[tb], p[tb + 1]);
                }
                pa[ks] = __builtin_bit_cast(short8, pw);
            }
#pragma unroll
            for (int nf = 0; nf < 4; ++nf) {
                cacc[nf] = __builtin_amdgcn_mfma_f32_16x16x32_bf16(pa[0], vf[nf][0], cacc[nf], 0, 0, 0);
                cacc[nf] = __builtin_amdgcn_mfma_f32_16x16x32_bf16(pa[1], vf[nf][1], cacc[nf], 0, 0, 0);
            }
        };

        smpv(sH, mH, lsH, caccH, qabsH, kt == qtH);
        if (doL) smpv(sL, mL, lsL, caccL, qabsL, kt == qtL);
        __syncthreads();
    }

    auto finish = [&](float lsum, f32x4(&cacc)[4], int qt) {
        float ls = lsum + __shfl_xor(lsum, 16);
        ls += __shfl_xor(ls, 32);
        float inv = 1.0f / ls;
#pragma unroll
        for (int i = 0; i < 4; ++i) {
            float li = __shfl(inv, lg * 4 + i);
            int srow = qt * 64 + w * 16 + lg * 4 + i;
            short* o = ctx + (size_t)(b * S_ + srow) * D_ + h * HD_ + lr;
#pragma unroll
            for (int nf = 0; nf < 4; ++nf) o[nf * 16] = f2bf(cacc[nf][i] * li);
        }
    };
    finish(lsH, caccH, qtH);
    finish(lsL, caccL, qtL);
}

// ---------------------------------------------------------------------------
extern "C" void kernel_launch(void* const* d_in, const int* in_sizes, int n_in,
                              void* d_out, int out_size, void* d_ws, size_t ws_size,
                              hipStream_t stream) {
    const float* x  = (const float*)d_in[0];
    const float* Wq = (const float*)d_in[1];
    const float* Wk = (const float*)d_in[2];
    const float* Wv = (const float*)d_in[3];
    const float* Wo = (const float*)d_in[4];
    const float* bo = (const float*)d_in[5];

    short* xb   = (short*)d_ws;                  // 4096*1024 bf16   (8 MB)
    short* Wqkv = xb + (size_t)BS_ * D_;         // 3072*1024 bf16   (6 MB)
    short* Wob  = Wqkv + (size_t)QKVN * D_;      // 1024*1024 bf16   (2 MB)
    short* qkb  = Wob + (size_t)D_ * D_;         // 4096*2048 bf16  (16 MB) Q|K
    short* ctxb = qkb + (size_t)BS_ * QKN;       // 4096*1024 bf16   (8 MB)
    short* vtg  = ctxb + (size_t)BS_ * D_;       // 2*16*64*2048 bf16 (8 MB) V^T

    const float qscale = 0.125f * 1.44269504089f;  // 1/sqrt(64) * log2(e)
    castall<<<2048, 256, 0, stream>>>(x, Wq, Wk, Wv, Wo, (short*)d_ws, qscale);

    // QKV projection: Q/K -> qkb [4096][2048]; V -> vtg (V^T, permuted)
    gemm_nt<2><<<dim3((BS_ / 128) * (QKVN / 128)), 256, 0, stream>>>(
        xb, Wqkv, qkb, nullptr, vtg, BS_, QKVN, D_);

    // causal attention -> ctx [4096,1024] bf16 (paired q-tiles)
    attn_fwd<<<dim3(S_ / 128, B_ * H_), 256, 0, stream>>>(qkb, vtg, ctxb);

    // output projection: out [4096,1024] f32 = ctxb @ Wob^T + bo
    gemm_nt<1><<<dim3((BS_ / 128) * (D_ / 128)), 256, 0, stream>>>(
        ctxb, Wob, d_out, bo, nullptr, BS_, D_, D_);
}